// Round 20
// baseline (185.639 us; speedup 1.0000x reference)
//
#include <hip/hip_runtime.h>
#include <hip/hip_bf16.h>

typedef unsigned short u16;
typedef unsigned int u32;
typedef unsigned long long u64;
typedef __attribute__((ext_vector_type(8))) short bf16x8;
typedef __attribute__((ext_vector_type(4))) float f32x4;
typedef __attribute__((ext_vector_type(4))) u16 u16x4;

#define N 4096
#define F 128
#define H 4
#define O 64
#define NW (N / 64)   // 64-bit words per adjacency row
#define NT 8          // KV tiles per column-half per z-slice (512/64)
#define NZ 4          // key-range slices (1024 keys each)
// log2(e)/8: folds the /sqrt(64) and the exp->exp2 conversion into Q.
#define QSCALE 0.18033688011112043f

__device__ inline float exp2_hw(float x) {
#if __has_builtin(__builtin_amdgcn_exp2f)
  return __builtin_amdgcn_exp2f(x);      // v_exp_f32, hazards handled by compiler
#else
  return __expf(x * 0.6931471805599453f);
#endif
}

__device__ inline u16 f2bf(float f) {           // RNE convert
  union { __hip_bfloat16 b; u16 u; } v;
  v.b = __float2bfloat16(f);
  return v.u;
}

__device__ inline float bf2f(u16 u) {
  union { float f; u32 i; } v; v.i = ((u32)u) << 16; return v.f;
}

// ---------------------------------------------------------------------------
// Fused prep: [0,1024) pack | [1024,1792) proj (bf16 MFMA) | [1792,1808) mask.
// (verbatim R14/R17 — verified)
// ---------------------------------------------------------------------------
__global__ __launch_bounds__(256) void prep_kernel(
    const float* __restrict__ x, const float* __restrict__ adj,
    const float* __restrict__ wv, const float* __restrict__ wq,
    const float* __restrict__ wk, u16* __restrict__ Q, u16* __restrict__ K,
    u16* __restrict__ Vt, float* __restrict__ rmask, u64* __restrict__ bits) {
  const int b = blockIdx.x;
  const int t = threadIdx.x;

  if (b < 1024) {
    // ---- pack: adjacency (0/1 fp32) -> bitmask ----
    const int w = t >> 6, l = t & 63;
    const int row = b * 4 + w;
    const float* ar = adj + (size_t)row * N;
    u64* br = bits + (size_t)row * NW;
#pragma unroll 4
    for (int j2 = 0; j2 < 16; j2++) {
      float4 v = *(const float4*)&ar[j2 * 256 + l * 4];
      unsigned nib = (unsigned)(v.x != 0.f) | ((unsigned)(v.y != 0.f) << 1) |
                     ((unsigned)(v.z != 0.f) << 2) | ((unsigned)(v.w != 0.f) << 3);
      u64 word = (u64)nib << ((l & 15) * 4);
      word |= __shfl_xor(word, 1);
      word |= __shfl_xor(word, 2);
      word |= __shfl_xor(word, 4);
      word |= __shfl_xor(word, 8);
      if ((l & 15) == 0) br[j2 * 4 + (l >> 4)] = word;
    }
  } else if (b < 1792) {
    // ---- proj: bf16 MFMA GEMM ----
    __shared__ __align__(16) u16 xb[64][136];
    __shared__ __align__(16) u16 wt[64][136];
    const int pb = b - 1024;
    const int brow = (pb & 63) * 64;
    const int p = pb >> 6, h = p / 3, which = p % 3;
    const float* W = (which == 0 ? wq : which == 1 ? wk : wv) + h * F * O;

#pragma unroll
    for (int i = 0; i < 8; i++) {          // x tile 64x128 fp32 -> bf16
      int idx = t + i * 256, r = idx >> 5, c4 = idx & 31;
      float4 v = *(const float4*)&x[(brow + r) * F + c4 * 4];
      u16x4 o4 = { f2bf(v.x), f2bf(v.y), f2bf(v.z), f2bf(v.w) };
      *(u16x4*)&xb[r][c4 * 4] = o4;
    }
#pragma unroll
    for (int i = 0; i < 8; i++) {          // W 128x64 fp32 -> wt[n][k] bf16
      int idx = t + i * 256, k = idx >> 4, n4 = idx & 15;
      float4 v = *(const float4*)&W[k * O + n4 * 4];
      wt[n4 * 4 + 0][k] = f2bf(v.x);
      wt[n4 * 4 + 1][k] = f2bf(v.y);
      wt[n4 * 4 + 2][k] = f2bf(v.z);
      wt[n4 * 4 + 3][k] = f2bf(v.w);
    }
    __syncthreads();

    const int w = t >> 6, l = t & 63;
    const int lm = l & 15, lg = l >> 4;
    const f32x4 z4 = {0.f, 0.f, 0.f, 0.f};
    bf16x8 af[4];
#pragma unroll
    for (int kc = 0; kc < 4; kc++)
      af[kc] = *(const bf16x8*)&xb[w * 16 + lm][kc * 32 + lg * 8];
    f32x4 acc[4];
#pragma unroll
    for (int ct = 0; ct < 4; ct++) {
      acc[ct] = z4;
#pragma unroll
      for (int kc = 0; kc < 4; kc++) {
        bf16x8 bfr = *(const bf16x8*)&wt[ct * 16 + lm][kc * 32 + lg * 8];
        acc[ct] = __builtin_amdgcn_mfma_f32_16x16x32_bf16(af[kc], bfr, acc[ct], 0, 0, 0);
      }
    }

    const int orow = brow + w * 16 + lg * 4;
    if (which == 0) {
      u16* dst = Q + h * N * O;
#pragma unroll
      for (int ct = 0; ct < 4; ct++)
#pragma unroll
        for (int r = 0; r < 4; r++)
          dst[(orow + r) * O + ct * 16 + lm] = f2bf(acc[ct][r] * QSCALE);
    } else if (which == 1) {
      u16* dst = K + h * N * O;
#pragma unroll
      for (int ct = 0; ct < 4; ct++)
#pragma unroll
        for (int r = 0; r < 4; r++)
          dst[(orow + r) * O + ct * 16 + lm] = f2bf(acc[ct][r]);
    } else {
      u16* dst = Vt + h * O * N;
#pragma unroll
      for (int ct = 0; ct < 4; ct++) {
        u16x4 v4 = { f2bf(acc[ct][0]), f2bf(acc[ct][1]),
                     f2bf(acc[ct][2]), f2bf(acc[ct][3]) };
        *(u16x4*)&dst[(size_t)(ct * 16 + lm) * N + orow] = v4;
      }
    }
  } else {
    // ---- mask ----
    int n = (b - 1792) * 256 + t;
    const float4* xr = (const float4*)(x + n * F);
    float s = 0.f;
#pragma unroll
    for (int i = 0; i < F / 4; i++) {
      float4 v = xr[i];
      s += fabsf(v.x) + fabsf(v.y) + fabsf(v.z) + fabsf(v.w);
    }
    rmask[n] = (s != 0.f) ? 1.f : 0.f;
  }
}

// ---------------------------------------------------------------------------
// Fused masked attention — swapped QK^T + thick waves (R17/R19-verified math),
// SINGLE-buffered kv for 4 blocks/CU: per iter STAGE(t) -> barrier ->
// compute(t) -> barrier. Exposed staging latency per block is hidden by the
// other 3 resident blocks (8 waves/SIMD). LDS = kv 32KB ∪ OmH u16[128][68]
// (17.4KB) + Ss2 1KB = 34.8KB -> 4 blocks/CU. VGPR pinned <=64 via
// __launch_bounds__(512,8).
// Epilogue: hc=1 waves park O-half as bf16 + S-half in LDS; hc=0 waves add
// in f32 and write Opart/Spart (one extra bf16 round on one half).
// grid (N/128, H, NZ=4); sigma key permutation keeps P lane-local for PV.
// ---------------------------------------------------------------------------
__global__ __launch_bounds__(512, 8) void attn_kernel(
    const u64* __restrict__ bits, const u16* __restrict__ Qg,
    const u16* __restrict__ Kg, const u16* __restrict__ Vtg,
    u16* __restrict__ Opart, float* __restrict__ Spart) {
  __shared__ __align__(16) char smem[33792];      // kv [4][8192] ∪ OmH [128][68] u16
  __shared__ float Ss2[8][32];                    // per-wave row-sums (2 q-sets)

  char (*kv)[8192] = (char (*)[8192])&smem[0];

  const int tid = threadIdx.x;
  const int w = tid >> 6, l = tid & 63;
  const int lm = l & 15, lg = l >> 4;
  const int rg = w >> 1, hc = w & 1;     // row-group 0..3 (32 rows), col-half
  const int h = blockIdx.y;
  const int z = blockIdx.z;              // key slice 0..3 (1024 keys each)
  const int R0 = blockIdx.x * 128;
  const int WR0 = R0 + rg * 32;          // this wave's 32 Q-rows
  const int CB0 = z * 1024;              // this block's key base

  const char* Kb = (const char*)(Kg + h * N * O);    // 128B per key-row
  const char* Vb = (const char*)(Vtg + h * O * N);   // 8KB per o-row
  const u64* bblk = bits + (size_t)WR0 * NW;

  // staging: lane fills LDS slot (row=w*8+(l>>3), col=(l&7)*16) linearly;
  // global source column inverse-swizzled with sw_idx(row).
  const int srow = w * 8 + (l >> 3);
  const int ssw = (((srow & 3) | (((srow >> 3) & 1) << 2)) << 4);
  const int scol = ((l & 7) * 16) ^ ssw;

  const int krow_base = (lm & 3) + 8 * (lm >> 2);
  const int ksw = (lm & 7) << 4;
  const int vsw = (((lm & 3) | (((lm >> 3) & 1) << 2)) << 4);

  // Q fragments for both q-sets (B-operand: col=lm=qrow, k=lg*8+j)
  const u16* Qh = Qg + h * N * O;
  bf16x8 qa0 = *(const bf16x8*)&Qh[(WR0 + lm) * O + lg * 8];
  bf16x8 qa1 = *(const bf16x8*)&Qh[(WR0 + lm) * O + 32 + lg * 8];
  bf16x8 qb0 = *(const bf16x8*)&Qh[(WR0 + 16 + lm) * O + lg * 8];
  bf16x8 qb1 = *(const bf16x8*)&Qh[(WR0 + 16 + lm) * O + 32 + lg * 8];

  bf16x8 ones;
#pragma unroll
  for (int i = 0; i < 8; i++) ones[i] = (short)0x3F80;

  f32x4 oaccA[4], oaccB[4];
  f32x4 laccA = {0.f, 0.f, 0.f, 0.f}, laccB = {0.f, 0.f, 0.f, 0.f};
#pragma unroll
  for (int i = 0; i < 4; i++) {
    oaccA[i] = (f32x4){0.f, 0.f, 0.f, 0.f};
    oaccB[i] = (f32x4){0.f, 0.f, 0.f, 0.f};
  }
  const f32x4 zero4 = {0.f, 0.f, 0.f, 0.f};

  auto STAGE = [&](int t) {
    __builtin_amdgcn_global_load_lds(
        (const u32*)(Kb + (size_t)(CB0 + 0 * 512 + t * 64 + srow) * 128 + scol),
        (u32*)&kv[0][w * 1024], 16, 0, 0);
    __builtin_amdgcn_global_load_lds(
        (const u32*)(Kb + (size_t)(CB0 + 1 * 512 + t * 64 + srow) * 128 + scol),
        (u32*)&kv[1][w * 1024], 16, 0, 0);
    __builtin_amdgcn_global_load_lds(
        (const u32*)(Vb + (size_t)srow * (N * 2) + (CB0 + 0 * 512 + t * 64) * 2 + scol),
        (u32*)&kv[2][w * 1024], 16, 0, 0);
    __builtin_amdgcn_global_load_lds(
        (const u32*)(Vb + (size_t)srow * (N * 2) + (CB0 + 1 * 512 + t * 64) * 2 + scol),
        (u32*)&kv[3][w * 1024], 16, 0, 0);
  };

#pragma unroll 1
  for (int t = 0; t < NT; ++t) {
    STAGE(t);
    __syncthreads();   // vmcnt drained (compiler) -> tile t ready for all waves

    const int widx = z * 16 + hc * NT + t;

    // bits: one word per lane per q-set
    u64 wordA = bblk[lm * NW + widx];
    u64 wordB = bblk[(16 + lm) * NW + widx];
    u64 wA = wordA >> (8 * lg);
    u64 wB = wordB >> (8 * lg);

    // ---- S^T = mfma(K, Q) for both q-sets, sharing the K reads ----
    const char* Kt = &kv[hc][0];
    f32x4 sA[4], sB[4];
    __builtin_amdgcn_s_setprio(1);
#pragma unroll
    for (int tt = 0; tt < 4; tt++) {
      const int row = krow_base + 4 * (tt & 1) + 32 * (tt >> 1);
      bf16x8 kb0 = *(const bf16x8*)(Kt + row * 128 + ((lg * 16) ^ ksw));
      bf16x8 kb1 = *(const bf16x8*)(Kt + row * 128 + ((lg * 16 + 64) ^ ksw));
      f32x4 t0 = __builtin_amdgcn_mfma_f32_16x16x32_bf16(kb0, qa0, zero4, 0, 0, 0);
      sA[tt] = __builtin_amdgcn_mfma_f32_16x16x32_bf16(kb1, qa1, t0, 0, 0, 0);
      f32x4 t1 = __builtin_amdgcn_mfma_f32_16x16x32_bf16(kb0, qb0, zero4, 0, 0, 0);
      sB[tt] = __builtin_amdgcn_mfma_f32_16x16x32_bf16(kb1, qb1, t1, 0, 0, 0);
    }
    __builtin_amdgcn_s_setprio(0);

    // ---- P = adj ? 2^(max(s,0.2s)) : 0 — in registers, both sets ----
    bf16x8 paA0, paA1, paB0, paB1;
    {
      float pv[4][4];
#pragma unroll
      for (int tt = 0; tt < 4; tt++)
#pragma unroll
        for (int r = 0; r < 4; r++) {
          unsigned bit = (unsigned)(wA >> (4 * (tt & 1) + 32 * (tt >> 1) + r)) & 1u;
          float sv = sA[tt][r];
          float lv = fmaxf(sv, 0.2f * sv);
          pv[tt][r] = bit ? exp2_hw(lv) : 0.f;
        }
#pragma unroll
      for (int r = 0; r < 4; r++) {
        paA0[r]     = (short)f2bf(pv[0][r]);
        paA0[4 + r] = (short)f2bf(pv[1][r]);
        paA1[r]     = (short)f2bf(pv[2][r]);
        paA1[4 + r] = (short)f2bf(pv[3][r]);
      }
    }
    {
      float pv[4][4];
#pragma unroll
      for (int tt = 0; tt < 4; tt++)
#pragma unroll
        for (int r = 0; r < 4; r++) {
          unsigned bit = (unsigned)(wB >> (4 * (tt & 1) + 32 * (tt >> 1) + r)) & 1u;
          float sv = sB[tt][r];
          float lv = fmaxf(sv, 0.2f * sv);
          pv[tt][r] = bit ? exp2_hw(lv) : 0.f;
        }
#pragma unroll
      for (int r = 0; r < 4; r++) {
        paB0[r]     = (short)f2bf(pv[0][r]);
        paB0[4 + r] = (short)f2bf(pv[1][r]);
        paB1[r]     = (short)f2bf(pv[2][r]);
        paB1[4 + r] = (short)f2bf(pv[3][r]);
      }
    }

    // ---- O^T += mfma(V, P) for both sets, sharing the V reads ----
    const char* Vt_ = &kv[2 + hc][0];
    __builtin_amdgcn_s_setprio(1);
#pragma unroll
    for (int ot = 0; ot < 4; ot++) {
      const int o = ot * 16 + lm;
      bf16x8 vb0 = *(const bf16x8*)(Vt_ + o * 128 + ((lg * 16) ^ vsw));
      bf16x8 vb1 = *(const bf16x8*)(Vt_ + o * 128 + ((lg * 16 + 64) ^ vsw));
      oaccA[ot] = __builtin_amdgcn_mfma_f32_16x16x32_bf16(vb0, paA0, oaccA[ot], 0, 0, 0);
      oaccA[ot] = __builtin_amdgcn_mfma_f32_16x16x32_bf16(vb1, paA1, oaccA[ot], 0, 0, 0);
      oaccB[ot] = __builtin_amdgcn_mfma_f32_16x16x32_bf16(vb0, paB0, oaccB[ot], 0, 0, 0);
      oaccB[ot] = __builtin_amdgcn_mfma_f32_16x16x32_bf16(vb1, paB1, oaccB[ot], 0, 0, 0);
    }
    laccA = __builtin_amdgcn_mfma_f32_16x16x32_bf16(ones, paA0, laccA, 0, 0, 0);
    laccA = __builtin_amdgcn_mfma_f32_16x16x32_bf16(ones, paA1, laccA, 0, 0, 0);
    laccB = __builtin_amdgcn_mfma_f32_16x16x32_bf16(ones, paB0, laccB, 0, 0, 0);
    laccB = __builtin_amdgcn_mfma_f32_16x16x32_bf16(ones, paB1, laccB, 0, 0, 0);
    __builtin_amdgcn_s_setprio(0);

    __syncthreads();   // all waves done reading kv before next STAGE overwrites
  }

  // ---- epilogue: hc=1 parks its halves (bf16 O, f32 S); hc=0 merges ----
  u16 (*OmH)[68] = (u16 (*)[68])&smem[0];   // [128][68] u16, 8B-aligned rows
  if (hc == 1) {
    const int r0 = rg * 32;
#pragma unroll
    for (int ot = 0; ot < 4; ot++) {
      u16x4 a = { f2bf(oaccA[ot][0]), f2bf(oaccA[ot][1]),
                  f2bf(oaccA[ot][2]), f2bf(oaccA[ot][3]) };
      *(u16x4*)&OmH[r0 + lm][ot * 16 + lg * 4] = a;
      u16x4 bq = { f2bf(oaccB[ot][0]), f2bf(oaccB[ot][1]),
                   f2bf(oaccB[ot][2]), f2bf(oaccB[ot][3]) };
      *(u16x4*)&OmH[r0 + 16 + lm][ot * 16 + lg * 4] = bq;
    }
    if (lg == 0) {
      Ss2[w][lm] = laccA[0];
      Ss2[w][16 + lm] = laccB[0];
    }
  }
  __syncthreads();
  if (hc == 0) {
    const int r0 = rg * 32;
    const size_t obase = ((size_t)z * H + h) * N;
#pragma unroll
    for (int ot = 0; ot < 4; ot++) {
      u16x4 hA = *(const u16x4*)&OmH[r0 + lm][ot * 16 + lg * 4];
      u16x4 hB = *(const u16x4*)&OmH[r0 + 16 + lm][ot * 16 + lg * 4];
      u16x4 oA = { f2bf(oaccA[ot][0] + bf2f(hA[0])), f2bf(oaccA[ot][1] + bf2f(hA[1])),
                   f2bf(oaccA[ot][2] + bf2f(hA[2])), f2bf(oaccA[ot][3] + bf2f(hA[3])) };
      u16x4 oB = { f2bf(oaccB[ot][0] + bf2f(hB[0])), f2bf(oaccB[ot][1] + bf2f(hB[1])),
                   f2bf(oaccB[ot][2] + bf2f(hB[2])), f2bf(oaccB[ot][3] + bf2f(hB[3])) };
      *(u16x4*)&Opart[(obase + R0 + r0 + lm) * O + ot * 16 + lg * 4] = oA;
      *(u16x4*)&Opart[(obase + R0 + r0 + 16 + lm) * O + ot * 16 + lg * 4] = oB;
    }
    if (lg == 0) {
      Spart[obase + R0 + r0 + lm] = laccA[0] + Ss2[w + 1][lm];
      Spart[obase + R0 + r0 + 16 + lm] = laccB[0] + Ss2[w + 1][16 + lm];
    }
  }
}

// ---------------------------------------------------------------------------
// Merge the NZ z-slices: out = relu((Σ O_z)/(Σ S_z)) * rowmask.
// ---------------------------------------------------------------------------
__global__ __launch_bounds__(256) void merge_kernel(
    const u16* __restrict__ Opart, const float* __restrict__ Spart,
    const float* __restrict__ rowmask, float* __restrict__ out) {
  const int h = blockIdx.y;
  const int idx = blockIdx.x * 256 + threadIdx.x;
  const int row = idx >> 4, c0 = (idx & 15) * 4;
  float S = 0.f;
#pragma unroll
  for (int z = 0; z < NZ; z++) S += Spart[((size_t)z * H + h) * N + row];
  float inv = (S > 0.f) ? 1.f / S : 0.f;
  float rm = rowmask[row];
  float a0 = 0.f, a1 = 0.f, a2 = 0.f, a3 = 0.f;
#pragma unroll
  for (int z = 0; z < NZ; z++) {
    u16x4 v = *(const u16x4*)&Opart[(((size_t)z * H + h) * N + row) * O + c0];
    a0 += bf2f(v[0]); a1 += bf2f(v[1]); a2 += bf2f(v[2]); a3 += bf2f(v[3]);
  }
  float4 r;
  r.x = fmaxf(a0 * inv, 0.f) * rm;
  r.y = fmaxf(a1 * inv, 0.f) * rm;
  r.z = fmaxf(a2 * inv, 0.f) * rm;
  r.w = fmaxf(a3 * inv, 0.f) * rm;
  *(float4*)&out[(size_t)row * (H * O) + h * O + c0] = r;
}

extern "C" void kernel_launch(void* const* d_in, const int* in_sizes, int n_in,
                              void* d_out, int out_size, void* d_ws, size_t ws_size,
                              hipStream_t stream) {
  const float* x   = (const float*)d_in[0];  // h [1,4096,128]
  const float* adj = (const float*)d_in[1];  // a [1,4096,4096]
  const float* wv  = (const float*)d_in[2];  // kernel      -> V
  const float* wq  = (const float*)d_in[3];  // attn_kernel -> Q (f_self)
  const float* wk  = (const float*)d_in[4];  // attn_kernel2-> K (f_other)
  float* out = (float*)d_out;

  u16* Q  = (u16*)d_ws;                     // [4][4096][64] bf16  (2 MB)
  u16* K  = Q + H * N * O;                  // [4][4096][64] bf16  (2 MB)
  u16* Vt = K + H * N * O;                  // [4][64][4096] bf16  (2 MB)
  float* rmask = (float*)(Vt + H * N * O);  // [4096] f32 (16 KB)
  u64* bits = (u64*)(rmask + N);            // [4096][64] u64 (2 MB)
  u16* Opart = (u16*)(bits + (size_t)N * NW);       // [4][4][4096][64] bf16 (8 MB)
  float* Spart = (float*)(Opart + (size_t)NZ * H * N * O);  // [4][4][4096] f32 (256 KB)

  prep_kernel<<<dim3(1808), 256, 0, stream>>>(x, adj, wv, wq, wk, Q, K, Vt, rmask, bits);
  attn_kernel<<<dim3(N / 128, H, NZ), 512, 0, stream>>>(bits, Q, K, Vt, Opart, Spart);
  merge_kernel<<<dim3(N * O / 4 / 256, H), 256, 0, stream>>>(Opart, Spart, rmask, out);
}

// Round 21
// 67.164 us; speedup vs baseline: 2.7640x; 2.7640x over previous
//
#include <hip/hip_runtime.h>
#include <hip/hip_bf16.h>

typedef unsigned short u16;
typedef unsigned int u32;
typedef unsigned long long u64;
typedef __attribute__((ext_vector_type(8))) short bf16x8;
typedef __attribute__((ext_vector_type(4))) float f32x4;
typedef __attribute__((ext_vector_type(4))) u16 u16x4;

#define N 4096
#define F 128
#define H 4
#define O 64
#define NW (N / 64)   // 64-bit words per adjacency row
#define NT 8          // KV tiles per column-half per z-slice (512/64)
#define NZ 4          // key-range slices (1024 keys each)
// log2(e)/8: folds the /sqrt(64) and the exp->exp2 conversion into Q.
#define QSCALE 0.18033688011112043f

__device__ inline float exp2_hw(float x) {
#if __has_builtin(__builtin_amdgcn_exp2f)
  return __builtin_amdgcn_exp2f(x);      // v_exp_f32, hazards handled by compiler
#else
  return __expf(x * 0.6931471805599453f);
#endif
}

__device__ inline u16 f2bf(float f) {           // RNE convert
  union { __hip_bfloat16 b; u16 u; } v;
  v.b = __float2bfloat16(f);
  return v.u;
}

__device__ inline float bf2f(u16 u) {
  union { float f; u32 i; } v; v.i = ((u32)u) << 16; return v.f;
}

// ---------------------------------------------------------------------------
// Fused prep: [0,1024) pack | [1024,1792) proj (bf16 MFMA) | [1792,1808) mask.
// (verbatim R14/R17 — verified)
// ---------------------------------------------------------------------------
__global__ __launch_bounds__(256) void prep_kernel(
    const float* __restrict__ x, const float* __restrict__ adj,
    const float* __restrict__ wv, const float* __restrict__ wq,
    const float* __restrict__ wk, u16* __restrict__ Q, u16* __restrict__ K,
    u16* __restrict__ Vt, float* __restrict__ rmask, u64* __restrict__ bits) {
  const int b = blockIdx.x;
  const int t = threadIdx.x;

  if (b < 1024) {
    // ---- pack: adjacency (0/1 fp32) -> bitmask ----
    const int w = t >> 6, l = t & 63;
    const int row = b * 4 + w;
    const float* ar = adj + (size_t)row * N;
    u64* br = bits + (size_t)row * NW;
#pragma unroll 4
    for (int j2 = 0; j2 < 16; j2++) {
      float4 v = *(const float4*)&ar[j2 * 256 + l * 4];
      unsigned nib = (unsigned)(v.x != 0.f) | ((unsigned)(v.y != 0.f) << 1) |
                     ((unsigned)(v.z != 0.f) << 2) | ((unsigned)(v.w != 0.f) << 3);
      u64 word = (u64)nib << ((l & 15) * 4);
      word |= __shfl_xor(word, 1);
      word |= __shfl_xor(word, 2);
      word |= __shfl_xor(word, 4);
      word |= __shfl_xor(word, 8);
      if ((l & 15) == 0) br[j2 * 4 + (l >> 4)] = word;
    }
  } else if (b < 1792) {
    // ---- proj: bf16 MFMA GEMM ----
    __shared__ __align__(16) u16 xb[64][136];
    __shared__ __align__(16) u16 wt[64][136];
    const int pb = b - 1024;
    const int brow = (pb & 63) * 64;
    const int p = pb >> 6, h = p / 3, which = p % 3;
    const float* W = (which == 0 ? wq : which == 1 ? wk : wv) + h * F * O;

#pragma unroll
    for (int i = 0; i < 8; i++) {          // x tile 64x128 fp32 -> bf16
      int idx = t + i * 256, r = idx >> 5, c4 = idx & 31;
      float4 v = *(const float4*)&x[(brow + r) * F + c4 * 4];
      u16x4 o4 = { f2bf(v.x), f2bf(v.y), f2bf(v.z), f2bf(v.w) };
      *(u16x4*)&xb[r][c4 * 4] = o4;
    }
#pragma unroll
    for (int i = 0; i < 8; i++) {          // W 128x64 fp32 -> wt[n][k] bf16
      int idx = t + i * 256, k = idx >> 4, n4 = idx & 15;
      float4 v = *(const float4*)&W[k * O + n4 * 4];
      wt[n4 * 4 + 0][k] = f2bf(v.x);
      wt[n4 * 4 + 1][k] = f2bf(v.y);
      wt[n4 * 4 + 2][k] = f2bf(v.z);
      wt[n4 * 4 + 3][k] = f2bf(v.w);
    }
    __syncthreads();

    const int w = t >> 6, l = t & 63;
    const int lm = l & 15, lg = l >> 4;
    const f32x4 z4 = {0.f, 0.f, 0.f, 0.f};
    bf16x8 af[4];
#pragma unroll
    for (int kc = 0; kc < 4; kc++)
      af[kc] = *(const bf16x8*)&xb[w * 16 + lm][kc * 32 + lg * 8];
    f32x4 acc[4];
#pragma unroll
    for (int ct = 0; ct < 4; ct++) {
      acc[ct] = z4;
#pragma unroll
      for (int kc = 0; kc < 4; kc++) {
        bf16x8 bfr = *(const bf16x8*)&wt[ct * 16 + lm][kc * 32 + lg * 8];
        acc[ct] = __builtin_amdgcn_mfma_f32_16x16x32_bf16(af[kc], bfr, acc[ct], 0, 0, 0);
      }
    }

    const int orow = brow + w * 16 + lg * 4;
    if (which == 0) {
      u16* dst = Q + h * N * O;
#pragma unroll
      for (int ct = 0; ct < 4; ct++)
#pragma unroll
        for (int r = 0; r < 4; r++)
          dst[(orow + r) * O + ct * 16 + lm] = f2bf(acc[ct][r] * QSCALE);
    } else if (which == 1) {
      u16* dst = K + h * N * O;
#pragma unroll
      for (int ct = 0; ct < 4; ct++)
#pragma unroll
        for (int r = 0; r < 4; r++)
          dst[(orow + r) * O + ct * 16 + lm] = f2bf(acc[ct][r]);
    } else {
      u16* dst = Vt + h * O * N;
#pragma unroll
      for (int ct = 0; ct < 4; ct++) {
        u16x4 v4 = { f2bf(acc[ct][0]), f2bf(acc[ct][1]),
                     f2bf(acc[ct][2]), f2bf(acc[ct][3]) };
        *(u16x4*)&dst[(size_t)(ct * 16 + lm) * N + orow] = v4;
      }
    }
  } else {
    // ---- mask ----
    int n = (b - 1792) * 256 + t;
    const float4* xr = (const float4*)(x + n * F);
    float s = 0.f;
#pragma unroll
    for (int i = 0; i < F / 4; i++) {
      float4 v = xr[i];
      s += fabsf(v.x) + fabsf(v.y) + fabsf(v.z) + fabsf(v.w);
    }
    rmask[n] = (s != 0.f) ? 1.f : 0.f;
  }
}

// ---------------------------------------------------------------------------
// Fused masked attention — swapped QK^T + thick waves (R17-verified), with
// the R18 keeper: epilogue Om2 padded to stride 66 (264B rows -> ~2-way
// banks). Double-buffered kv, natural VGPR (64), 2 blocks/CU.
// grid (N/128, H, NZ=4), block 512 = 4 rg x 2 hc; NT=8 iters/z-slice.
// sigma(tt,i) key permutation keeps P lane-local for PV. Swizzle sw_idx(row)
// on staging source + ds_read (rule #21). Row-sums via ones-MFMA.
// LDS: smem 67584 (kv 64KB ∪ Om2 [2][128][66]) + Ss2 1KB -> 2 blocks/CU.
// ---------------------------------------------------------------------------
__global__ __launch_bounds__(512, 4) void attn_kernel(
    const u64* __restrict__ bits, const u16* __restrict__ Qg,
    const u16* __restrict__ Kg, const u16* __restrict__ Vtg,
    u16* __restrict__ Opart, float* __restrict__ Spart) {
  __shared__ __align__(16) char smem[67584];      // kv [2][4][8192] ∪ Om2
  __shared__ float Ss2[8][32];                    // per-wave row-sums (2 q-sets)

  char (*kv)[4][8192] = (char (*)[4][8192])&smem[0];

  const int tid = threadIdx.x;
  const int w = tid >> 6, l = tid & 63;
  const int lm = l & 15, lg = l >> 4;
  const int rg = w >> 1, hc = w & 1;     // row-group 0..3 (32 rows), col-half
  const int h = blockIdx.y;
  const int z = blockIdx.z;              // key slice 0..3 (1024 keys each)
  const int R0 = blockIdx.x * 128;
  const int WR0 = R0 + rg * 32;          // this wave's 32 Q-rows
  const int CB0 = z * 1024;              // this block's key base

  const char* Kb = (const char*)(Kg + h * N * O);    // 128B per key-row
  const char* Vb = (const char*)(Vtg + h * O * N);   // 8KB per o-row
  const u64* bblk = bits + (size_t)WR0 * NW;

  // staging: lane fills LDS slot (row=w*8+(l>>3), col=(l&7)*16) linearly;
  // global source column inverse-swizzled with sw_idx(row).
  const int srow = w * 8 + (l >> 3);
  const int ssw = (((srow & 3) | (((srow >> 3) & 1) << 2)) << 4);
  const int scol = ((l & 7) * 16) ^ ssw;

  const int krow_base = (lm & 3) + 8 * (lm >> 2);
  const int ksw = (lm & 7) << 4;
  const int vsw = (((lm & 3) | (((lm >> 3) & 1) << 2)) << 4);

  // Q fragments for both q-sets (B-operand: col=lm=qrow, k=lg*8+j)
  const u16* Qh = Qg + h * N * O;
  bf16x8 qa0 = *(const bf16x8*)&Qh[(WR0 + lm) * O + lg * 8];
  bf16x8 qa1 = *(const bf16x8*)&Qh[(WR0 + lm) * O + 32 + lg * 8];
  bf16x8 qb0 = *(const bf16x8*)&Qh[(WR0 + 16 + lm) * O + lg * 8];
  bf16x8 qb1 = *(const bf16x8*)&Qh[(WR0 + 16 + lm) * O + 32 + lg * 8];

  bf16x8 ones;
#pragma unroll
  for (int i = 0; i < 8; i++) ones[i] = (short)0x3F80;

  f32x4 oaccA[4], oaccB[4];
  f32x4 laccA = {0.f, 0.f, 0.f, 0.f}, laccB = {0.f, 0.f, 0.f, 0.f};
#pragma unroll
  for (int i = 0; i < 4; i++) {
    oaccA[i] = (f32x4){0.f, 0.f, 0.f, 0.f};
    oaccB[i] = (f32x4){0.f, 0.f, 0.f, 0.f};
  }
  const f32x4 zero4 = {0.f, 0.f, 0.f, 0.f};

  auto STAGE = [&](int b, int t) {
    __builtin_amdgcn_global_load_lds(
        (const u32*)(Kb + (size_t)(CB0 + 0 * 512 + t * 64 + srow) * 128 + scol),
        (u32*)&kv[b][0][w * 1024], 16, 0, 0);
    __builtin_amdgcn_global_load_lds(
        (const u32*)(Kb + (size_t)(CB0 + 1 * 512 + t * 64 + srow) * 128 + scol),
        (u32*)&kv[b][1][w * 1024], 16, 0, 0);
    __builtin_amdgcn_global_load_lds(
        (const u32*)(Vb + (size_t)srow * (N * 2) + (CB0 + 0 * 512 + t * 64) * 2 + scol),
        (u32*)&kv[b][2][w * 1024], 16, 0, 0);
    __builtin_amdgcn_global_load_lds(
        (const u32*)(Vb + (size_t)srow * (N * 2) + (CB0 + 1 * 512 + t * 64) * 2 + scol),
        (u32*)&kv[b][3][w * 1024], 16, 0, 0);
  };

  STAGE(0, 0);
  __syncthreads();

  int b = 0;
#pragma unroll 1
  for (int t = 0; t < NT; ++t) {
    if (t + 1 < NT) STAGE(b ^ 1, t + 1);   // prefetch next tile (other buffer)

    const int widx = z * 16 + hc * NT + t;

    // bits: one word per lane per q-set
    u64 wordA = bblk[lm * NW + widx];
    u64 wordB = bblk[(16 + lm) * NW + widx];
    u64 wA = wordA >> (8 * lg);
    u64 wB = wordB >> (8 * lg);

    // ---- S^T = mfma(K, Q) for both q-sets, sharing the K reads ----
    const char* Kt = &kv[b][hc][0];
    f32x4 sA[4], sB[4];
    __builtin_amdgcn_s_setprio(1);
#pragma unroll
    for (int tt = 0; tt < 4; tt++) {
      const int row = krow_base + 4 * (tt & 1) + 32 * (tt >> 1);
      bf16x8 kb0 = *(const bf16x8*)(Kt + row * 128 + ((lg * 16) ^ ksw));
      bf16x8 kb1 = *(const bf16x8*)(Kt + row * 128 + ((lg * 16 + 64) ^ ksw));
      f32x4 t0 = __builtin_amdgcn_mfma_f32_16x16x32_bf16(kb0, qa0, zero4, 0, 0, 0);
      sA[tt] = __builtin_amdgcn_mfma_f32_16x16x32_bf16(kb1, qa1, t0, 0, 0, 0);
      f32x4 t1 = __builtin_amdgcn_mfma_f32_16x16x32_bf16(kb0, qb0, zero4, 0, 0, 0);
      sB[tt] = __builtin_amdgcn_mfma_f32_16x16x32_bf16(kb1, qb1, t1, 0, 0, 0);
    }
    __builtin_amdgcn_s_setprio(0);

    // ---- P = adj ? 2^(max(s,0.2s)) : 0 — in registers, both sets ----
    bf16x8 paA0, paA1, paB0, paB1;
    {
      float pv[4][4];
#pragma unroll
      for (int tt = 0; tt < 4; tt++)
#pragma unroll
        for (int r = 0; r < 4; r++) {
          unsigned bit = (unsigned)(wA >> (4 * (tt & 1) + 32 * (tt >> 1) + r)) & 1u;
          float sv = sA[tt][r];
          float lv = fmaxf(sv, 0.2f * sv);
          pv[tt][r] = bit ? exp2_hw(lv) : 0.f;
        }
#pragma unroll
      for (int r = 0; r < 4; r++) {
        paA0[r]     = (short)f2bf(pv[0][r]);
        paA0[4 + r] = (short)f2bf(pv[1][r]);
        paA1[r]     = (short)f2bf(pv[2][r]);
        paA1[4 + r] = (short)f2bf(pv[3][r]);
      }
    }
    {
      float pv[4][4];
#pragma unroll
      for (int tt = 0; tt < 4; tt++)
#pragma unroll
        for (int r = 0; r < 4; r++) {
          unsigned bit = (unsigned)(wB >> (4 * (tt & 1) + 32 * (tt >> 1) + r)) & 1u;
          float sv = sB[tt][r];
          float lv = fmaxf(sv, 0.2f * sv);
          pv[tt][r] = bit ? exp2_hw(lv) : 0.f;
        }
#pragma unroll
      for (int r = 0; r < 4; r++) {
        paB0[r]     = (short)f2bf(pv[0][r]);
        paB0[4 + r] = (short)f2bf(pv[1][r]);
        paB1[r]     = (short)f2bf(pv[2][r]);
        paB1[4 + r] = (short)f2bf(pv[3][r]);
      }
    }

    // ---- O^T += mfma(V, P) for both sets, sharing the V reads ----
    const char* Vt_ = &kv[b][2 + hc][0];
    __builtin_amdgcn_s_setprio(1);
#pragma unroll
    for (int ot = 0; ot < 4; ot++) {
      const int o = ot * 16 + lm;
      bf16x8 vb0 = *(const bf16x8*)(Vt_ + o * 128 + ((lg * 16) ^ vsw));
      bf16x8 vb1 = *(const bf16x8*)(Vt_ + o * 128 + ((lg * 16 + 64) ^ vsw));
      oaccA[ot] = __builtin_amdgcn_mfma_f32_16x16x32_bf16(vb0, paA0, oaccA[ot], 0, 0, 0);
      oaccA[ot] = __builtin_amdgcn_mfma_f32_16x16x32_bf16(vb1, paA1, oaccA[ot], 0, 0, 0);
      oaccB[ot] = __builtin_amdgcn_mfma_f32_16x16x32_bf16(vb0, paB0, oaccB[ot], 0, 0, 0);
      oaccB[ot] = __builtin_amdgcn_mfma_f32_16x16x32_bf16(vb1, paB1, oaccB[ot], 0, 0, 0);
    }
    laccA = __builtin_amdgcn_mfma_f32_16x16x32_bf16(ones, paA0, laccA, 0, 0, 0);
    laccA = __builtin_amdgcn_mfma_f32_16x16x32_bf16(ones, paA1, laccA, 0, 0, 0);
    laccB = __builtin_amdgcn_mfma_f32_16x16x32_bf16(ones, paB0, laccB, 0, 0, 0);
    laccB = __builtin_amdgcn_mfma_f32_16x16x32_bf16(ones, paB1, laccB, 0, 0, 0);
    __builtin_amdgcn_s_setprio(0);

    __syncthreads();   // drains prefetch + protects buffer flip
    b ^= 1;
  }

  // ---- merge the 2 hc halves in LDS (Om2 aliases kv; barrier-safe).
  // Stride 66 floats (264B rows) -> ~2-way banks on writes AND reads. ----
  float (*Om2)[128][66] = (float (*)[128][66])&smem[0];
#pragma unroll
  for (int ot = 0; ot < 4; ot++) {
    *(f32x4*)&Om2[hc][rg * 32 + lm][ot * 16 + lg * 4] = oaccA[ot];
    *(f32x4*)&Om2[hc][rg * 32 + 16 + lm][ot * 16 + lg * 4] = oaccB[ot];
  }
  if (lg == 0) {
    Ss2[w][lm] = laccA[0];
    Ss2[w][16 + lm] = laccB[0];
  }
  __syncthreads();

  // ---- write partials: Opart bf16 [z][h][row][col], Spart f32 [z][h][row] ----
#pragma unroll
  for (int rr = 0; rr < 2; rr++) {
    const int row = rr * 64 + (tid >> 3);   // 0..127
    const int c0 = (tid & 7) * 8;           // 0..56
    const int grow = R0 + row;
    u16* op = &Opart[(((size_t)z * H + h) * N + grow) * O + c0];
    u16x4 v0 = { f2bf(Om2[0][row][c0 + 0] + Om2[1][row][c0 + 0]),
                 f2bf(Om2[0][row][c0 + 1] + Om2[1][row][c0 + 1]),
                 f2bf(Om2[0][row][c0 + 2] + Om2[1][row][c0 + 2]),
                 f2bf(Om2[0][row][c0 + 3] + Om2[1][row][c0 + 3]) };
    u16x4 v1 = { f2bf(Om2[0][row][c0 + 4] + Om2[1][row][c0 + 4]),
                 f2bf(Om2[0][row][c0 + 5] + Om2[1][row][c0 + 5]),
                 f2bf(Om2[0][row][c0 + 6] + Om2[1][row][c0 + 6]),
                 f2bf(Om2[0][row][c0 + 7] + Om2[1][row][c0 + 7]) };
    *(u16x4*)&op[0] = v0;
    *(u16x4*)&op[4] = v1;
    if ((tid & 7) == 0) {
      const int rg2 = row >> 5, ri = row & 31;
      Spart[((size_t)z * H + h) * N + grow] = Ss2[rg2 * 2 + 0][ri] + Ss2[rg2 * 2 + 1][ri];
    }
  }
}

// ---------------------------------------------------------------------------
// Merge the NZ z-slices: out = relu((Σ O_z)/(Σ S_z)) * rowmask.
// ---------------------------------------------------------------------------
__global__ __launch_bounds__(256) void merge_kernel(
    const u16* __restrict__ Opart, const float* __restrict__ Spart,
    const float* __restrict__ rowmask, float* __restrict__ out) {
  const int h = blockIdx.y;
  const int idx = blockIdx.x * 256 + threadIdx.x;
  const int row = idx >> 4, c0 = (idx & 15) * 4;
  float S = 0.f;
#pragma unroll
  for (int z = 0; z < NZ; z++) S += Spart[((size_t)z * H + h) * N + row];
  float inv = (S > 0.f) ? 1.f / S : 0.f;
  float rm = rowmask[row];
  float a0 = 0.f, a1 = 0.f, a2 = 0.f, a3 = 0.f;
#pragma unroll
  for (int z = 0; z < NZ; z++) {
    u16x4 v = *(const u16x4*)&Opart[(((size_t)z * H + h) * N + row) * O + c0];
    a0 += bf2f(v[0]); a1 += bf2f(v[1]); a2 += bf2f(v[2]); a3 += bf2f(v[3]);
  }
  float4 r;
  r.x = fmaxf(a0 * inv, 0.f) * rm;
  r.y = fmaxf(a1 * inv, 0.f) * rm;
  r.z = fmaxf(a2 * inv, 0.f) * rm;
  r.w = fmaxf(a3 * inv, 0.f) * rm;
  *(float4*)&out[(size_t)row * (H * O) + h * O + c0] = r;
}

extern "C" void kernel_launch(void* const* d_in, const int* in_sizes, int n_in,
                              void* d_out, int out_size, void* d_ws, size_t ws_size,
                              hipStream_t stream) {
  const float* x   = (const float*)d_in[0];  // h [1,4096,128]
  const float* adj = (const float*)d_in[1];  // a [1,4096,4096]
  const float* wv  = (const float*)d_in[2];  // kernel      -> V
  const float* wq  = (const float*)d_in[3];  // attn_kernel -> Q (f_self)
  const float* wk  = (const float*)d_in[4];  // attn_kernel2-> K (f_other)
  float* out = (float*)d_out;

  u16* Q  = (u16*)d_ws;                     // [4][4096][64] bf16  (2 MB)
  u16* K  = Q + H * N * O;                  // [4][4096][64] bf16  (2 MB)
  u16* Vt = K + H * N * O;                  // [4][64][4096] bf16  (2 MB)
  float* rmask = (float*)(Vt + H * N * O);  // [4096] f32 (16 KB)
  u64* bits = (u64*)(rmask + N);            // [4096][64] u64 (2 MB)
  u16* Opart = (u16*)(bits + (size_t)N * NW);       // [4][4][4096][64] bf16 (8 MB)
  float* Spart = (float*)(Opart + (size_t)NZ * H * N * O);  // [4][4][4096] f32 (256 KB)

  prep_kernel<<<dim3(1808), 256, 0, stream>>>(x, adj, wv, wq, wk, Q, K, Vt, rmask, bits);
  attn_kernel<<<dim3(N / 128, H, NZ), 512, 0, stream>>>(bits, Q, K, Vt, Opart, Spart);
  merge_kernel<<<dim3(N * O / 4 / 256, H), 256, 0, stream>>>(Opart, Spart, rmask, out);
}